// Round 1
// baseline (329.585 us; speedup 1.0000x reference)
//
#include <hip/hip_runtime.h>
#include <stdint.h>

typedef short bf8 __attribute__((ext_vector_type(8)));     // 8 x bf16 (4 VGPR)
typedef float f32x4 __attribute__((ext_vector_type(4)));

#define LN_EPS 1e-5f

__device__ __forceinline__ uint16_t f2bf(float f) {
    uint32_t u = __float_as_uint(f);
    u = (u + 0x7FFFu + ((u >> 16) & 1u)) >> 16;   // RNE
    return (uint16_t)u;
}

__device__ __forceinline__ void gld16(const void* g, void* l) {
    __builtin_amdgcn_global_load_lds(
        (const __attribute__((address_space(1))) uint32_t*)(uintptr_t)g,
        (__attribute__((address_space(3))) uint32_t*)(uint32_t)(uintptr_t)l,
        16, 0, 0);
}

// ---------------- fp32 -> bf16 convert (up to 4 arrays per launch) -------------
__global__ void cvt_bf16(const float* __restrict__ s0, const float* __restrict__ s1,
                         const float* __restrict__ s2, const float* __restrict__ s3,
                         uint16_t* d0, uint16_t* d1, uint16_t* d2, uint16_t* d3, int n4) {
    const float* ss[4] = {s0, s1, s2, s3};
    uint16_t*    dd[4] = {d0, d1, d2, d3};
    const float* s = ss[blockIdx.z];
    uint16_t*    d = dd[blockIdx.z];
    int i = blockIdx.x * blockDim.x + threadIdx.x;
    int stride = gridDim.x * blockDim.x;
    for (; i < n4; i += stride) {
        float4 f = ((const float4*)s)[i];
        ushort4 u;
        u.x = f2bf(f.x); u.y = f2bf(f.y); u.z = f2bf(f.z); u.w = f2bf(f.w);
        ((ushort4*)d)[i] = u;
    }
}

// ---------------- GEMM: C[r][c] = (sum_d A[r][d]*Bw[c][d] + bias[c]) * scale ----
// mode 0: out bf16 at [(b*16+h)*1024 + l]*64 + d      (Q/K head layout)
// mode 2: out bf16 at [(b*16+h)*64 + d]*1024 + l      (V transposed)
// mode 3: out fp32 plain [r*1024 + c]                 (FC)
__global__ __launch_bounds__(256) void gemm_bt(
        const uint16_t* __restrict__ A, const uint16_t* __restrict__ Bw,
        const float* __restrict__ bias, void* __restrict__ out,
        int Kd, int mode, float scale) {
    __shared__ uint16_t As[2][128][64];
    __shared__ uint16_t Bs[2][128][64];
    const int tid = threadIdx.x;
    const int lane = tid & 63, w = tid >> 6;
    const int wr = w >> 1, wc = w & 1;
    const int tm = blockIdx.y * 128, tn = blockIdx.x * 128;

    f32x4 acc[4][4] = {};

    auto stage = [&](int buf, int kt) {
#pragma unroll
        for (int j = 0; j < 4; ++j) {
            int rr = (w * 4 + j) * 8 + (lane >> 3);
            int cc = (lane & 7) * 8;
            gld16(A + (size_t)(tm + rr) * Kd + kt * 64 + cc, &As[buf][rr][cc]);
            gld16(Bw + (size_t)(tn + rr) * Kd + kt * 64 + cc, &Bs[buf][rr][cc]);
        }
    };

    stage(0, 0);
    __syncthreads();
    const int nk = Kd / 64;
    for (int kt = 0; kt < nk; ++kt) {
        int buf = kt & 1;
        if (kt + 1 < nk) stage(buf ^ 1, kt + 1);
#pragma unroll
        for (int kk = 0; kk < 2; ++kk) {
            bf8 af[4], bfr[4];
#pragma unroll
            for (int m = 0; m < 4; ++m)
                af[m] = *(const bf8*)&As[buf][wr * 64 + m * 16 + (lane & 15)][kk * 32 + (lane >> 4) * 8];
#pragma unroll
            for (int n = 0; n < 4; ++n)
                bfr[n] = *(const bf8*)&Bs[buf][wc * 64 + n * 16 + (lane & 15)][kk * 32 + (lane >> 4) * 8];
#pragma unroll
            for (int m = 0; m < 4; ++m)
#pragma unroll
                for (int n = 0; n < 4; ++n)
                    acc[m][n] = __builtin_amdgcn_mfma_f32_16x16x32_bf16(af[m], bfr[n], acc[m][n], 0, 0, 0);
        }
        __syncthreads();
    }

#pragma unroll
    for (int m = 0; m < 4; ++m) {
        int r0 = tm + wr * 64 + m * 16 + (lane >> 4) * 4;
#pragma unroll
        for (int n = 0; n < 4; ++n) {
            int c = tn + wc * 64 + n * 16 + (lane & 15);
            float bv = bias[c];
#pragma unroll
            for (int i = 0; i < 4; ++i) {
                int r = r0 + i;
                float v2 = (acc[m][n][i] + bv) * scale;
                if (mode == 3) {
                    ((float*)out)[(size_t)r * 1024 + c] = v2;
                } else {
                    int b = r >> 10, l = r & 1023;
                    int h = c >> 6, d = c & 63;
                    size_t idx = (mode == 2)
                        ? (((size_t)(b * 16 + h) * 64 + d) * 1024 + l)
                        : (((size_t)(b * 16 + h) * 1024 + l) * 64 + d);
                    ((uint16_t*)out)[idx] = f2bf(v2);
                }
            }
        }
    }
}

// ---------------- fused scores + mask + softmax + PV ---------------------------
// grid: (64 = b*16+h, 32 = q-block of 32 rows), 256 threads (4 waves)
__global__ __launch_bounds__(256) void attn_fused(
        const uint16_t* __restrict__ qh, const uint16_t* __restrict__ kh,
        const uint16_t* __restrict__ vt, const int* __restrict__ mask,
        float* __restrict__ attn_out, uint16_t* __restrict__ ctx) {
    __shared__ float S[32][1024];   // 128 KB
    const int tid = threadIdx.x, lane = tid & 63, w = tid >> 6;
    const int bh = blockIdx.x;
    const int b = bh >> 4, h = bh & 15;
    const int q0 = blockIdx.y * 32;

    const uint16_t* Q = qh + ((size_t)bh * 1024 + q0) * 64;
    const uint16_t* K = kh + (size_t)bh * 1024 * 64;
    const uint16_t* V = vt + (size_t)bh * 64 * 1024;

    // Q fragments (scaled by 1/8 already at projection time)
    bf8 aq[2][2];
#pragma unroll
    for (int fr = 0; fr < 2; ++fr)
#pragma unroll
        for (int kk = 0; kk < 2; ++kk)
            aq[fr][kk] = *(const bf8*)&Q[(size_t)(fr * 16 + (lane & 15)) * 64 + kk * 32 + (lane >> 4) * 8];

    // scores: wave w owns key-columns [w*256, w*256+256)
    for (int cf = 0; cf < 16; ++cf) {
        int nc = w * 256 + cf * 16;
        bf8 bk[2];
#pragma unroll
        for (int kk = 0; kk < 2; ++kk)
            bk[kk] = *(const bf8*)&K[(size_t)(nc + (lane & 15)) * 64 + kk * 32 + (lane >> 4) * 8];
        f32x4 s[2] = {};
#pragma unroll
        for (int kk = 0; kk < 2; ++kk)
#pragma unroll
            for (int fr = 0; fr < 2; ++fr)
                s[fr] = __builtin_amdgcn_mfma_f32_16x16x32_bf16(aq[fr][kk], bk[kk], s[fr], 0, 0, 0);
#pragma unroll
        for (int fr = 0; fr < 2; ++fr) {
            int row = fr * 16 + (lane >> 4) * 4;
#pragma unroll
            for (int i = 0; i < 4; ++i)
                S[row + i][nc + (lane & 15)] = s[fr][i];
        }
    }
    __syncthreads();

    // softmax: wave w owns rows [w*8, w*8+8); all 64 lanes per row
    const size_t mbase = ((size_t)b * 1024 + q0) * 1024;
    float* arow = attn_out + (((size_t)(h * 4 + b) * 1024) + q0) * 1024;
    for (int rr = 0; rr < 8; ++rr) {
        int row = w * 8 + rr;
        float p[16];
        float mx = -__builtin_inff();
#pragma unroll
        for (int i = 0; i < 8; ++i) {
            int kx = lane * 2 + i * 128;
            float2 sv = *(const float2*)&S[row][kx];
            int2 mv = *(const int2*)&mask[mbase + (size_t)row * 1024 + kx];
            float a0 = mv.x ? -__builtin_inff() : sv.x;
            float a1 = mv.y ? -__builtin_inff() : sv.y;
            p[2 * i] = a0; p[2 * i + 1] = a1;
            mx = fmaxf(mx, fmaxf(a0, a1));
        }
#pragma unroll
        for (int off = 32; off; off >>= 1) mx = fmaxf(mx, __shfl_xor(mx, off));
        float sum = 0.f;
#pragma unroll
        for (int i = 0; i < 16; ++i) {
            float e = (p[i] == -__builtin_inff()) ? 0.f : __expf(p[i] - mx);
            p[i] = e; sum += e;
        }
#pragma unroll
        for (int off = 32; off; off >>= 1) sum += __shfl_xor(sum, off);
        float inv = 1.f / sum;
        // write fp32 attn (coalesced) + bf16 P into LDS (in-place, XOR-swizzled)
        char* prow = (char*)&S[row][0];
#pragma unroll
        for (int i = 0; i < 8; ++i) {
            int kx = lane * 2 + i * 128;
            float2 ov; ov.x = p[2 * i] * inv; ov.y = p[2 * i + 1] * inv;
            *(float2*)&arow[(size_t)row * 1024 + kx] = ov;
            uint32_t pk = (uint32_t)f2bf(ov.x) | ((uint32_t)f2bf(ov.y) << 16);
            int boff = (kx * 2) ^ ((row & 7) << 4);
            *(uint32_t*)(prow + boff) = pk;
        }
    }
    __syncthreads();

    // PV: wave w owns d-columns [w*16, w*16+16)
    f32x4 o[2] = {};
    const char* Pbase = (const char*)&S[0][0];
    for (int ks = 0; ks < 32; ++ks) {
        bf8 bv = *(const bf8*)&V[(size_t)(w * 16 + (lane & 15)) * 1024 + ks * 32 + (lane >> 4) * 8];
#pragma unroll
        for (int fr = 0; fr < 2; ++fr) {
            int row = fr * 16 + (lane & 15);
            int kbyte = (ks * 32 + (lane >> 4) * 8) * 2;
            bf8 ap = *(const bf8*)(Pbase + (size_t)row * 4096 + (kbyte ^ ((row & 7) << 4)));
            o[fr] = __builtin_amdgcn_mfma_f32_16x16x32_bf16(ap, bv, o[fr], 0, 0, 0);
        }
    }
#pragma unroll
    for (int fr = 0; fr < 2; ++fr) {
        int d = h * 64 + w * 16 + (lane & 15);
#pragma unroll
        for (int i = 0; i < 4; ++i) {
            int qrow = q0 + fr * 16 + (lane >> 4) * 4 + i;
            ctx[(size_t)(b * 1024 + qrow) * 1024 + d] = f2bf(o[fr][i]);
        }
    }
}

// ---------------- residual + LayerNorm -----------------------------------------
__global__ __launch_bounds__(256) void fc_ln(
        const float* __restrict__ fcout, const float* __restrict__ resid,
        const float* __restrict__ g, const float* __restrict__ bb,
        float* __restrict__ y) {
    const int r = blockIdx.x, tid = threadIdx.x;
    const int lane = tid & 63, w = tid >> 6;
    __shared__ float red[8];
    float4 xv = ((const float4*)(fcout + (size_t)r * 1024))[tid];
    float4 rv = ((const float4*)(resid + (size_t)r * 1024))[tid];
    float x[4] = {xv.x + rv.x, xv.y + rv.y, xv.z + rv.z, xv.w + rv.w};
    float s = x[0] + x[1] + x[2] + x[3];
    float s2 = x[0] * x[0] + x[1] * x[1] + x[2] * x[2] + x[3] * x[3];
#pragma unroll
    for (int off = 32; off; off >>= 1) { s += __shfl_xor(s, off); s2 += __shfl_xor(s2, off); }
    if (lane == 0) { red[w] = s; red[4 + w] = s2; }
    __syncthreads();
    s = red[0] + red[1] + red[2] + red[3];
    s2 = red[4] + red[5] + red[6] + red[7];
    float mu = s * (1.f / 1024.f);
    float var = s2 * (1.f / 1024.f) - mu * mu;
    float inv = rsqrtf(var + LN_EPS);
    float4 gv = ((const float4*)g)[tid];
    float4 bv = ((const float4*)bb)[tid];
    float4 ov;
    ov.x = (x[0] - mu) * inv * gv.x + bv.x;
    ov.y = (x[1] - mu) * inv * gv.y + bv.y;
    ov.z = (x[2] - mu) * inv * gv.z + bv.z;
    ov.w = (x[3] - mu) * inv * gv.w + bv.w;
    ((float4*)(y + (size_t)r * 1024))[tid] = ov;
}

extern "C" void kernel_launch(void* const* d_in, const int* in_sizes, int n_in,
                              void* d_out, int out_size, void* d_ws, size_t ws_size,
                              hipStream_t stream) {
    const float* q    = (const float*)d_in[0];
    const float* k    = (const float*)d_in[1];
    const float* v    = (const float*)d_in[2];
    const int*   mask = (const int*)d_in[3];
    const float* wq_w = (const float*)d_in[4];
    const float* wq_b = (const float*)d_in[5];
    const float* wk_w = (const float*)d_in[6];
    const float* wk_b = (const float*)d_in[7];
    const float* wv_w = (const float*)d_in[8];
    const float* wv_b = (const float*)d_in[9];
    const float* fc_w = (const float*)d_in[10];
    const float* fc_b = (const float*)d_in[11];
    const float* ln_g = (const float*)d_in[12];
    const float* ln_b = (const float*)d_in[13];

    char* ws = (char*)d_ws;
    uint16_t* qb  = (uint16_t*)(ws);                    // 8 MB bf16 q
    uint16_t* kb  = (uint16_t*)(ws + (8u << 20));
    uint16_t* vb  = (uint16_t*)(ws + (16u << 20));
    uint16_t* wqb = (uint16_t*)(ws + (24u << 20));      // 2 MB each
    uint16_t* wkb = (uint16_t*)(ws + (26u << 20));
    uint16_t* wvb = (uint16_t*)(ws + (28u << 20));
    uint16_t* wfb = (uint16_t*)(ws + (30u << 20));
    uint16_t* qhb = (uint16_t*)(ws + (32u << 20));      // [bh][l][64]
    uint16_t* khb = (uint16_t*)(ws + (40u << 20));
    uint16_t* vtb = (uint16_t*)(ws + (48u << 20));      // [bh][d][l]
    uint16_t* ctx = (uint16_t*)(ws + (56u << 20));      // [b*l][1024]
    float*    fco = (float*)(ws + (64u << 20));         // 16 MB fp32

    float* y_out = (float*)d_out;
    float* attn_out = y_out + (size_t)4 * 1024 * 1024;

    cvt_bf16<<<dim3(256, 1, 3), 256, 0, stream>>>(q, k, v, nullptr, qb, kb, vb, nullptr, (4 << 20) / 4);
    cvt_bf16<<<dim3(64, 1, 4), 256, 0, stream>>>(wq_w, wk_w, wv_w, fc_w, wqb, wkb, wvb, wfb, (1 << 20) / 4);

    dim3 gg(8, 32);
    gemm_bt<<<gg, 256, 0, stream>>>(qb, wqb, wq_b, qhb, 1024, 0, 0.125f);
    gemm_bt<<<gg, 256, 0, stream>>>(kb, wkb, wk_b, khb, 1024, 0, 1.0f);
    gemm_bt<<<gg, 256, 0, stream>>>(vb, wvb, wv_b, vtb, 1024, 2, 1.0f);

    attn_fused<<<dim3(64, 32), 256, 0, stream>>>(qhb, khb, vtb, mask, attn_out, ctx);

    gemm_bt<<<gg, 256, 0, stream>>>(ctx, wfb, fc_b, fco, 1024, 3, 1.0f);

    fc_ln<<<4096, 256, 0, stream>>>(fco, q, ln_g, ln_b, y_out);
}

// Round 2
// 311.418 us; speedup vs baseline: 1.0583x; 1.0583x over previous
//
#include <hip/hip_runtime.h>
#include <stdint.h>

typedef short bf8 __attribute__((ext_vector_type(8)));     // 8 x bf16 (4 VGPR)
typedef float f32x4 __attribute__((ext_vector_type(4)));

#define LN_EPS 1e-5f

__device__ __forceinline__ uint16_t f2bf(float f) {
    uint32_t u = __float_as_uint(f);
    u = (u + 0x7FFFu + ((u >> 16) & 1u)) >> 16;   // RNE
    return (uint16_t)u;
}

__device__ __forceinline__ void gld16(const void* g, void* l) {
    __builtin_amdgcn_global_load_lds(
        (const __attribute__((address_space(1))) uint32_t*)(uintptr_t)g,
        (__attribute__((address_space(3))) uint32_t*)(uint32_t)(uintptr_t)l,
        16, 0, 0);
}

// ---------------- fp32 -> bf16 convert (up to 4 arrays per launch) -------------
__global__ void cvt_bf16(const float* __restrict__ s0, const float* __restrict__ s1,
                         const float* __restrict__ s2, const float* __restrict__ s3,
                         uint16_t* d0, uint16_t* d1, uint16_t* d2, uint16_t* d3, int n4) {
    const float* ss[4] = {s0, s1, s2, s3};
    uint16_t*    dd[4] = {d0, d1, d2, d3};
    const float* s = ss[blockIdx.z];
    uint16_t*    d = dd[blockIdx.z];
    int i = blockIdx.x * blockDim.x + threadIdx.x;
    int stride = gridDim.x * blockDim.x;
    for (; i < n4; i += stride) {
        float4 f = ((const float4*)s)[i];
        ushort4 u;
        u.x = f2bf(f.x); u.y = f2bf(f.y); u.z = f2bf(f.z); u.w = f2bf(f.w);
        ((ushort4*)d)[i] = u;
    }
}

// ---------------- GEMM: C[r][c] = (sum_d A[r][d]*Bw[c][d] + bias[c]) * scale ----
// mode 0: out bf16 at [(b*16+h)*1024 + l]*64 + d      (Q/K head layout)
// mode 2: out bf16 at [(b*16+h)*64 + d]*1024 + l      (V transposed)
// mode 3: out fp32 plain [r*1024 + c]                 (FC)
__global__ __launch_bounds__(256) void gemm_bt(
        const uint16_t* __restrict__ A, const uint16_t* __restrict__ Bw,
        const float* __restrict__ bias, void* __restrict__ out,
        int Kd, int mode, float scale) {
    __shared__ uint16_t As[2][128][64];
    __shared__ uint16_t Bs[2][128][64];
    const int tid = threadIdx.x;
    const int lane = tid & 63, w = tid >> 6;
    const int wr = w >> 1, wc = w & 1;
    const int tm = blockIdx.y * 128, tn = blockIdx.x * 128;

    f32x4 acc[4][4] = {};

    auto stage = [&](int buf, int kt) {
#pragma unroll
        for (int j = 0; j < 4; ++j) {
            int rr = (w * 4 + j) * 8 + (lane >> 3);
            int cc = (lane & 7) * 8;
            gld16(A + (size_t)(tm + rr) * Kd + kt * 64 + cc, &As[buf][rr][cc]);
            gld16(Bw + (size_t)(tn + rr) * Kd + kt * 64 + cc, &Bs[buf][rr][cc]);
        }
    };

    stage(0, 0);
    __syncthreads();
    const int nk = Kd / 64;
    for (int kt = 0; kt < nk; ++kt) {
        int buf = kt & 1;
        if (kt + 1 < nk) stage(buf ^ 1, kt + 1);
#pragma unroll
        for (int kk = 0; kk < 2; ++kk) {
            bf8 af[4], bfr[4];
#pragma unroll
            for (int m = 0; m < 4; ++m)
                af[m] = *(const bf8*)&As[buf][wr * 64 + m * 16 + (lane & 15)][kk * 32 + (lane >> 4) * 8];
#pragma unroll
            for (int n = 0; n < 4; ++n)
                bfr[n] = *(const bf8*)&Bs[buf][wc * 64 + n * 16 + (lane & 15)][kk * 32 + (lane >> 4) * 8];
#pragma unroll
            for (int m = 0; m < 4; ++m)
#pragma unroll
                for (int n = 0; n < 4; ++n)
                    acc[m][n] = __builtin_amdgcn_mfma_f32_16x16x32_bf16(af[m], bfr[n], acc[m][n], 0, 0, 0);
        }
        __syncthreads();
    }

#pragma unroll
    for (int m = 0; m < 4; ++m) {
        int r0 = tm + wr * 64 + m * 16 + (lane >> 4) * 4;
#pragma unroll
        for (int n = 0; n < 4; ++n) {
            int c = tn + wc * 64 + n * 16 + (lane & 15);
            float bv = bias[c];
#pragma unroll
            for (int i = 0; i < 4; ++i) {
                int r = r0 + i;
                float v2 = (acc[m][n][i] + bv) * scale;
                if (mode == 3) {
                    ((float*)out)[(size_t)r * 1024 + c] = v2;
                } else {
                    int b = r >> 10, l = r & 1023;
                    int h = c >> 6, d = c & 63;
                    size_t idx = (mode == 2)
                        ? (((size_t)(b * 16 + h) * 64 + d) * 1024 + l)
                        : (((size_t)(b * 16 + h) * 1024 + l) * 64 + d);
                    ((uint16_t*)out)[idx] = f2bf(v2);
                }
            }
        }
    }
}

// ---------------- fused scores + mask + softmax + PV ---------------------------
// grid: (64 = b*16+h, 32 = q-block of 32 rows), 512 threads (8 waves)
#define SSTRIDE 1028   // floats per row: 1028*4 = 4112 B, 16B aligned, good bank spread
__global__ __launch_bounds__(512) void attn_fused(
        const uint16_t* __restrict__ qh, const uint16_t* __restrict__ kh,
        const uint16_t* __restrict__ vt, const int* __restrict__ mask,
        float* __restrict__ attn_out, uint16_t* __restrict__ ctx) {
    __shared__ float S[32][SSTRIDE];   // ~128.5 KB
    const int tid = threadIdx.x, lane = tid & 63, w = tid >> 6;
    const int bh = blockIdx.x;
    const int b = bh >> 4, h = bh & 15;
    const int q0 = blockIdx.y * 32;

    const uint16_t* Q = qh + ((size_t)bh * 1024 + q0) * 64;
    const uint16_t* K = kh + (size_t)bh * 1024 * 64;
    const uint16_t* V = vt + (size_t)bh * 64 * 1024;

    // Q fragments (scaled by 1/8 already at projection time)
    bf8 aq[2][2];
#pragma unroll
    for (int fr = 0; fr < 2; ++fr)
#pragma unroll
        for (int kk = 0; kk < 2; ++kk)
            aq[fr][kk] = *(const bf8*)&Q[(size_t)(fr * 16 + (lane & 15)) * 64 + kk * 32 + (lane >> 4) * 8];

    // phase 1 -- scores: wave w owns key-columns [w*128, w*128+128)
    for (int cf = 0; cf < 8; ++cf) {
        int nc = w * 128 + cf * 16;
        bf8 bk[2];
#pragma unroll
        for (int kk = 0; kk < 2; ++kk)
            bk[kk] = *(const bf8*)&K[(size_t)(nc + (lane & 15)) * 64 + kk * 32 + (lane >> 4) * 8];
        f32x4 s[2] = {};
#pragma unroll
        for (int kk = 0; kk < 2; ++kk)
#pragma unroll
            for (int fr = 0; fr < 2; ++fr)
                s[fr] = __builtin_amdgcn_mfma_f32_16x16x32_bf16(aq[fr][kk], bk[kk], s[fr], 0, 0, 0);
#pragma unroll
        for (int fr = 0; fr < 2; ++fr) {
            int row = fr * 16 + (lane >> 4) * 4;
#pragma unroll
            for (int i = 0; i < 4; ++i)
                S[row + i][nc + (lane & 15)] = s[fr][i];
        }
    }
    __syncthreads();

    // phase 2 -- softmax: wave w owns rows [w*4, w*4+4); 16 elems/lane, 16B I/O
    const size_t mbase = ((size_t)b * 1024 + q0) * 1024;
    float* arow = attn_out + (((size_t)(h * 4 + b) * 1024) + q0) * 1024;
    for (int rr = 0; rr < 4; ++rr) {
        int row = w * 4 + rr;
        float* Srow = &S[row][0];
        float p[16];
        float mx = -__builtin_inff();
#pragma unroll
        for (int i = 0; i < 4; ++i) {
            int kx = lane * 4 + i * 256;
            float4 sv = *(const float4*)&Srow[kx];
            int4 mv = *(const int4*)&mask[mbase + (size_t)row * 1024 + kx];
            float a0 = mv.x ? -__builtin_inff() : sv.x;
            float a1 = mv.y ? -__builtin_inff() : sv.y;
            float a2 = mv.z ? -__builtin_inff() : sv.z;
            float a3 = mv.w ? -__builtin_inff() : sv.w;
            p[4 * i] = a0; p[4 * i + 1] = a1; p[4 * i + 2] = a2; p[4 * i + 3] = a3;
            mx = fmaxf(mx, fmaxf(fmaxf(a0, a1), fmaxf(a2, a3)));
        }
#pragma unroll
        for (int off = 32; off; off >>= 1) mx = fmaxf(mx, __shfl_xor(mx, off));
        float sum = 0.f;
#pragma unroll
        for (int i = 0; i < 16; ++i) {
            float e = (p[i] == -__builtin_inff()) ? 0.f : __expf(p[i] - mx);
            p[i] = e; sum += e;
        }
#pragma unroll
        for (int off = 32; off; off >>= 1) sum += __shfl_xor(sum, off);
        float inv = 1.f / sum;
        // write fp32 attn (float4, coalesced) + bf16 P into LDS (in-place, front of row)
        char* prow = (char*)Srow;
#pragma unroll
        for (int i = 0; i < 4; ++i) {
            int kx = lane * 4 + i * 256;
            float4 ov;
            ov.x = p[4 * i] * inv; ov.y = p[4 * i + 1] * inv;
            ov.z = p[4 * i + 2] * inv; ov.w = p[4 * i + 3] * inv;
            *(float4*)&arow[(size_t)row * 1024 + kx] = ov;
            uint2 pk;
            pk.x = (uint32_t)f2bf(ov.x) | ((uint32_t)f2bf(ov.y) << 16);
            pk.y = (uint32_t)f2bf(ov.z) | ((uint32_t)f2bf(ov.w) << 16);
            *(uint2*)(prow + kx * 2) = pk;
        }
    }
    __syncthreads();

    // phase 3 -- PV: one 16x16 output tile per wave: fr = w>>2, dc = w&3
    const int fr = w >> 2, dc = w & 3;
    f32x4 o = {};
    const char* Pbase = (const char*)&S[0][0];
    const int prow = fr * 16 + (lane & 15);
    const char* Prow = Pbase + (size_t)prow * (SSTRIDE * 4);
    for (int ks = 0; ks < 32; ++ks) {
        bf8 bv = *(const bf8*)&V[(size_t)(dc * 16 + (lane & 15)) * 1024 + ks * 32 + (lane >> 4) * 8];
        bf8 ap = *(const bf8*)(Prow + ks * 64 + (lane >> 4) * 16);
        o = __builtin_amdgcn_mfma_f32_16x16x32_bf16(ap, bv, o, 0, 0, 0);
    }
    {
        int d = h * 64 + dc * 16 + (lane & 15);
#pragma unroll
        for (int i = 0; i < 4; ++i) {
            int qrow = q0 + fr * 16 + (lane >> 4) * 4 + i;
            ctx[(size_t)(b * 1024 + qrow) * 1024 + d] = f2bf(o[i]);
        }
    }
}

// ---------------- residual + LayerNorm -----------------------------------------
__global__ __launch_bounds__(256) void fc_ln(
        const float* __restrict__ fcout, const float* __restrict__ resid,
        const float* __restrict__ g, const float* __restrict__ bb,
        float* __restrict__ y) {
    const int r = blockIdx.x, tid = threadIdx.x;
    const int lane = tid & 63, w = tid >> 6;
    __shared__ float red[8];
    float4 xv = ((const float4*)(fcout + (size_t)r * 1024))[tid];
    float4 rv = ((const float4*)(resid + (size_t)r * 1024))[tid];
    float x[4] = {xv.x + rv.x, xv.y + rv.y, xv.z + rv.z, xv.w + rv.w};
    float s = x[0] + x[1] + x[2] + x[3];
    float s2 = x[0] * x[0] + x[1] * x[1] + x[2] * x[2] + x[3] * x[3];
#pragma unroll
    for (int off = 32; off; off >>= 1) { s += __shfl_xor(s, off); s2 += __shfl_xor(s2, off); }
    if (lane == 0) { red[w] = s; red[4 + w] = s2; }
    __syncthreads();
    s = red[0] + red[1] + red[2] + red[3];
    s2 = red[4] + red[5] + red[6] + red[7];
    float mu = s * (1.f / 1024.f);
    float var = s2 * (1.f / 1024.f) - mu * mu;
    float inv = rsqrtf(var + LN_EPS);
    float4 gv = ((const float4*)g)[tid];
    float4 bv = ((const float4*)bb)[tid];
    float4 ov;
    ov.x = (x[0] - mu) * inv * gv.x + bv.x;
    ov.y = (x[1] - mu) * inv * gv.y + bv.y;
    ov.z = (x[2] - mu) * inv * gv.z + bv.z;
    ov.w = (x[3] - mu) * inv * gv.w + bv.w;
    ((float4*)(y + (size_t)r * 1024))[tid] = ov;
}

extern "C" void kernel_launch(void* const* d_in, const int* in_sizes, int n_in,
                              void* d_out, int out_size, void* d_ws, size_t ws_size,
                              hipStream_t stream) {
    const float* q    = (const float*)d_in[0];
    const float* k    = (const float*)d_in[1];
    const float* v    = (const float*)d_in[2];
    const int*   mask = (const int*)d_in[3];
    const float* wq_w = (const float*)d_in[4];
    const float* wq_b = (const float*)d_in[5];
    const float* wk_w = (const float*)d_in[6];
    const float* wk_b = (const float*)d_in[7];
    const float* wv_w = (const float*)d_in[8];
    const float* wv_b = (const float*)d_in[9];
    const float* fc_w = (const float*)d_in[10];
    const float* fc_b = (const float*)d_in[11];
    const float* ln_g = (const float*)d_in[12];
    const float* ln_b = (const float*)d_in[13];

    char* ws = (char*)d_ws;
    uint16_t* qb  = (uint16_t*)(ws);                    // 8 MB bf16 q
    uint16_t* kb  = (uint16_t*)(ws + (8u << 20));
    uint16_t* vb  = (uint16_t*)(ws + (16u << 20));
    uint16_t* wqb = (uint16_t*)(ws + (24u << 20));      // 2 MB each
    uint16_t* wkb = (uint16_t*)(ws + (26u << 20));
    uint16_t* wvb = (uint16_t*)(ws + (28u << 20));
    uint16_t* wfb = (uint16_t*)(ws + (30u << 20));
    uint16_t* qhb = (uint16_t*)(ws + (32u << 20));      // [bh][l][64]
    uint16_t* khb = (uint16_t*)(ws + (40u << 20));
    uint16_t* vtb = (uint16_t*)(ws + (48u << 20));      // [bh][d][l]
    uint16_t* ctx = (uint16_t*)(ws + (56u << 20));      // [b*l][1024]
    float*    fco = (float*)(ws + (64u << 20));         // 16 MB fp32

    float* y_out = (float*)d_out;
    float* attn_out = y_out + (size_t)4 * 1024 * 1024;

    cvt_bf16<<<dim3(256, 1, 3), 256, 0, stream>>>(q, k, v, nullptr, qb, kb, vb, nullptr, (4 << 20) / 4);
    cvt_bf16<<<dim3(64, 1, 4), 256, 0, stream>>>(wq_w, wk_w, wv_w, fc_w, wqb, wkb, wvb, wfb, (1 << 20) / 4);

    dim3 gg(8, 32);
    gemm_bt<<<gg, 256, 0, stream>>>(qb, wqb, wq_b, qhb, 1024, 0, 0.125f);
    gemm_bt<<<gg, 256, 0, stream>>>(kb, wkb, wk_b, khb, 1024, 0, 1.0f);
    gemm_bt<<<gg, 256, 0, stream>>>(vb, wvb, wv_b, vtb, 1024, 2, 1.0f);

    attn_fused<<<dim3(64, 32), 512, 0, stream>>>(qhb, khb, vtb, mask, attn_out, ctx);

    gemm_bt<<<gg, 256, 0, stream>>>(ctx, wfb, fc_b, fco, 1024, 3, 1.0f);

    fc_ln<<<4096, 256, 0, stream>>>(fco, q, ln_g, ln_b, y_out);
}

// Round 3
// 286.535 us; speedup vs baseline: 1.1502x; 1.0868x over previous
//
#include <hip/hip_runtime.h>
#include <stdint.h>

typedef short bf8 __attribute__((ext_vector_type(8)));     // 8 x bf16 (4 VGPR)
typedef float f32x4 __attribute__((ext_vector_type(4)));

#define LN_EPS 1e-5f

__device__ __forceinline__ uint16_t f2bf(float f) {
    uint32_t u = __float_as_uint(f);
    u = (u + 0x7FFFu + ((u >> 16) & 1u)) >> 16;   // RNE
    return (uint16_t)u;
}

__device__ __forceinline__ void gld16(const void* g, void* l) {
    __builtin_amdgcn_global_load_lds(
        (const __attribute__((address_space(1))) uint32_t*)(uintptr_t)g,
        (__attribute__((address_space(3))) uint32_t*)(uint32_t)(uintptr_t)l,
        16, 0, 0);
}

// ---------------- fp32 -> bf16 convert (up to 4 arrays per launch) -------------
__global__ void cvt_bf16(const float* __restrict__ s0, const float* __restrict__ s1,
                         const float* __restrict__ s2, const float* __restrict__ s3,
                         uint16_t* d0, uint16_t* d1, uint16_t* d2, uint16_t* d3, int n4) {
    const float* ss[4] = {s0, s1, s2, s3};
    uint16_t*    dd[4] = {d0, d1, d2, d3};
    const float* s = ss[blockIdx.z];
    uint16_t*    d = dd[blockIdx.z];
    int i = blockIdx.x * blockDim.x + threadIdx.x;
    int stride = gridDim.x * blockDim.x;
    for (; i < n4; i += stride) {
        float4 f = ((const float4*)s)[i];
        ushort4 u;
        u.x = f2bf(f.x); u.y = f2bf(f.y); u.z = f2bf(f.z); u.w = f2bf(f.w);
        ((ushort4*)d)[i] = u;
    }
}

// ---------------- GEMM: C[r][c] = (sum_d A[r][d]*Bw[c][d] + bias[c]) * scale ----
// mode 0: out bf16 at [(b*16+h)*1024 + l]*64 + d      (Q/K head layout)
// mode 2: out bf16 at [(b*16+h)*64 + d]*1024 + l      (V transposed)
// mode 3: out fp32 plain [r*1024 + c]                 (FC)
__global__ __launch_bounds__(256) void gemm_bt(
        const uint16_t* __restrict__ A, const uint16_t* __restrict__ Bw,
        const float* __restrict__ bias, void* __restrict__ out,
        int Kd, int mode, float scale) {
    __shared__ uint16_t As[2][128][64];
    __shared__ uint16_t Bs[2][128][64];
    const int tid = threadIdx.x;
    const int lane = tid & 63, w = tid >> 6;
    const int wr = w >> 1, wc = w & 1;
    const int tm = blockIdx.y * 128, tn = blockIdx.x * 128;

    f32x4 acc[4][4] = {};

    auto stage = [&](int buf, int kt) {
#pragma unroll
        for (int j = 0; j < 4; ++j) {
            int rr = (w * 4 + j) * 8 + (lane >> 3);
            int cc = (lane & 7) * 8;
            gld16(A + (size_t)(tm + rr) * Kd + kt * 64 + cc, &As[buf][rr][cc]);
            gld16(Bw + (size_t)(tn + rr) * Kd + kt * 64 + cc, &Bs[buf][rr][cc]);
        }
    };

    stage(0, 0);
    __syncthreads();
    const int nk = Kd / 64;
    for (int kt = 0; kt < nk; ++kt) {
        int buf = kt & 1;
        if (kt + 1 < nk) stage(buf ^ 1, kt + 1);
#pragma unroll
        for (int kk = 0; kk < 2; ++kk) {
            bf8 af[4], bfr[4];
#pragma unroll
            for (int m = 0; m < 4; ++m)
                af[m] = *(const bf8*)&As[buf][wr * 64 + m * 16 + (lane & 15)][kk * 32 + (lane >> 4) * 8];
#pragma unroll
            for (int n = 0; n < 4; ++n)
                bfr[n] = *(const bf8*)&Bs[buf][wc * 64 + n * 16 + (lane & 15)][kk * 32 + (lane >> 4) * 8];
#pragma unroll
            for (int m = 0; m < 4; ++m)
#pragma unroll
                for (int n = 0; n < 4; ++n)
                    acc[m][n] = __builtin_amdgcn_mfma_f32_16x16x32_bf16(af[m], bfr[n], acc[m][n], 0, 0, 0);
        }
        __syncthreads();
    }

#pragma unroll
    for (int m = 0; m < 4; ++m) {
        int r0 = tm + wr * 64 + m * 16 + (lane >> 4) * 4;
#pragma unroll
        for (int n = 0; n < 4; ++n) {
            int c = tn + wc * 64 + n * 16 + (lane & 15);
            float bv = bias[c];
#pragma unroll
            for (int i = 0; i < 4; ++i) {
                int r = r0 + i;
                float v2 = (acc[m][n][i] + bv) * scale;
                if (mode == 3) {
                    ((float*)out)[(size_t)r * 1024 + c] = v2;
                } else {
                    int b = r >> 10, l = r & 1023;
                    int h = c >> 6, d = c & 63;
                    size_t idx = (mode == 2)
                        ? (((size_t)(b * 16 + h) * 64 + d) * 1024 + l)
                        : (((size_t)(b * 16 + h) * 1024 + l) * 64 + d);
                    ((uint16_t*)out)[idx] = f2bf(v2);
                }
            }
        }
    }
}

// ---------------- fused scores + mask + softmax + PV ---------------------------
// grid: (64 = q-block of 16 rows, 64 = b*16+h), 512 threads (8 waves)
// LDS ~70 KB -> 2 blocks/CU, 16 waves/CU.
#define QB 16
#define SSTRIDE 1028   // floats per row: 4112 B, 16B aligned, 2-way-max bank spread
__global__ __launch_bounds__(512, 4) void attn_fused(
        const uint16_t* __restrict__ qh, const uint16_t* __restrict__ kh,
        const uint16_t* __restrict__ vt, const int* __restrict__ mask,
        float* __restrict__ attn_out, uint16_t* __restrict__ ctx) {
    __shared__ float S[QB][SSTRIDE];    // 65792 B
    __shared__ float Opart[16][68];     // 4352 B (k-half partial of PV)
    const int tid = threadIdx.x, lane = tid & 63, w = tid >> 6;
    const int bh = blockIdx.y;
    const int b = bh >> 4, h = bh & 15;
    const int q0 = blockIdx.x * QB;

    const uint16_t* Q = qh + ((size_t)bh * 1024 + q0) * 64;
    const uint16_t* K = kh + (size_t)bh * 1024 * 64;
    const uint16_t* V = vt + (size_t)bh * 64 * 1024;

    // Q fragments for rows q0..q0+15 (scaled by 1/8 at projection time)
    bf8 aq[2];
#pragma unroll
    for (int kk = 0; kk < 2; ++kk)
        aq[kk] = *(const bf8*)&Q[(size_t)(lane & 15) * 64 + kk * 32 + (lane >> 4) * 8];

    // phase 1 -- scores: wave w owns key-columns [w*128, w*128+128)
    for (int cf = 0; cf < 8; ++cf) {
        int nc = w * 128 + cf * 16;
        bf8 bk0 = *(const bf8*)&K[(size_t)(nc + (lane & 15)) * 64 + (lane >> 4) * 8];
        bf8 bk1 = *(const bf8*)&K[(size_t)(nc + (lane & 15)) * 64 + 32 + (lane >> 4) * 8];
        f32x4 s = {};
        s = __builtin_amdgcn_mfma_f32_16x16x32_bf16(aq[0], bk0, s, 0, 0, 0);
        s = __builtin_amdgcn_mfma_f32_16x16x32_bf16(aq[1], bk1, s, 0, 0, 0);
#pragma unroll
        for (int i = 0; i < 4; ++i)
            S[(lane >> 4) * 4 + i][nc + (lane & 15)] = s[i];
    }
    __syncthreads();

    // phase 2 -- softmax: wave w owns rows [w*2, w*2+2); 16 elems/lane, 16B I/O
    const size_t mbase = ((size_t)b * 1024 + q0) * 1024;
    float* arow = attn_out + (((size_t)(h * 4 + b) * 1024) + q0) * 1024;
    for (int rr = 0; rr < 2; ++rr) {
        int row = w * 2 + rr;
        float* Srow = &S[row][0];
        float p[16];
        float mx = -__builtin_inff();
#pragma unroll
        for (int i = 0; i < 4; ++i) {
            int kx = lane * 4 + i * 256;
            float4 sv = *(const float4*)&Srow[kx];
            int4 mv = *(const int4*)&mask[mbase + (size_t)row * 1024 + kx];
            float a0 = mv.x ? -__builtin_inff() : sv.x;
            float a1 = mv.y ? -__builtin_inff() : sv.y;
            float a2 = mv.z ? -__builtin_inff() : sv.z;
            float a3 = mv.w ? -__builtin_inff() : sv.w;
            p[4 * i] = a0; p[4 * i + 1] = a1; p[4 * i + 2] = a2; p[4 * i + 3] = a3;
            mx = fmaxf(mx, fmaxf(fmaxf(a0, a1), fmaxf(a2, a3)));
        }
#pragma unroll
        for (int off = 32; off; off >>= 1) mx = fmaxf(mx, __shfl_xor(mx, off));
        float sum = 0.f;
#pragma unroll
        for (int i = 0; i < 16; ++i) {
            float e = (p[i] == -__builtin_inff()) ? 0.f : __expf(p[i] - mx);
            p[i] = e; sum += e;
        }
#pragma unroll
        for (int off = 32; off; off >>= 1) sum += __shfl_xor(sum, off);
        float inv = 1.f / sum;
        // write fp32 attn (float4, coalesced) + bf16 P into LDS (in-place, front of row)
        char* prow = (char*)Srow;
#pragma unroll
        for (int i = 0; i < 4; ++i) {
            int kx = lane * 4 + i * 256;
            float4 ov;
            ov.x = p[4 * i] * inv; ov.y = p[4 * i + 1] * inv;
            ov.z = p[4 * i + 2] * inv; ov.w = p[4 * i + 3] * inv;
            *(float4*)&arow[(size_t)row * 1024 + kx] = ov;
            uint2 pk;
            pk.x = (uint32_t)f2bf(ov.x) | ((uint32_t)f2bf(ov.y) << 16);
            pk.y = (uint32_t)f2bf(ov.z) | ((uint32_t)f2bf(ov.w) << 16);
            *(uint2*)(prow + kx * 2) = pk;
        }
    }
    __syncthreads();

    // phase 3 -- PV: wave w -> d-chunk (w&3)*16, k-half (w>>2)*512
    const int dc = w & 3, khf = w >> 2;
    f32x4 o = {};
    const char* Prow = (const char*)&S[lane & 15][0];
    for (int t = 0; t < 16; ++t) {
        int ks = khf * 16 + t;
        bf8 bv = *(const bf8*)&V[(size_t)(dc * 16 + (lane & 15)) * 1024 + ks * 32 + (lane >> 4) * 8];
        bf8 ap = *(const bf8*)(Prow + ks * 64 + (lane >> 4) * 16);
        o = __builtin_amdgcn_mfma_f32_16x16x32_bf16(ap, bv, o, 0, 0, 0);
    }
    if (khf == 1) {
#pragma unroll
        for (int i = 0; i < 4; ++i)
            Opart[(lane >> 4) * 4 + i][dc * 16 + (lane & 15)] = o[i];
    }
    __syncthreads();
    if (khf == 0) {
        int d = h * 64 + dc * 16 + (lane & 15);
#pragma unroll
        for (int i = 0; i < 4; ++i) {
            int qrow = q0 + (lane >> 4) * 4 + i;
            float val = o[i] + Opart[(lane >> 4) * 4 + i][dc * 16 + (lane & 15)];
            ctx[(size_t)(b * 1024 + qrow) * 1024 + d] = f2bf(val);
        }
    }
}

// ---------------- residual + LayerNorm -----------------------------------------
__global__ __launch_bounds__(256) void fc_ln(
        const float* __restrict__ fcout, const float* __restrict__ resid,
        const float* __restrict__ g, const float* __restrict__ bb,
        float* __restrict__ y) {
    const int r = blockIdx.x, tid = threadIdx.x;
    const int lane = tid & 63, w = tid >> 6;
    __shared__ float red[8];
    float4 xv = ((const float4*)(fcout + (size_t)r * 1024))[tid];
    float4 rv = ((const float4*)(resid + (size_t)r * 1024))[tid];
    float x[4] = {xv.x + rv.x, xv.y + rv.y, xv.z + rv.z, xv.w + rv.w};
    float s = x[0] + x[1] + x[2] + x[3];
    float s2 = x[0] * x[0] + x[1] * x[1] + x[2] * x[2] + x[3] * x[3];
#pragma unroll
    for (int off = 32; off; off >>= 1) { s += __shfl_xor(s, off); s2 += __shfl_xor(s2, off); }
    if (lane == 0) { red[w] = s; red[4 + w] = s2; }
    __syncthreads();
    s = red[0] + red[1] + red[2] + red[3];
    s2 = red[4] + red[5] + red[6] + red[7];
    float mu = s * (1.f / 1024.f);
    float var = s2 * (1.f / 1024.f) - mu * mu;
    float inv = rsqrtf(var + LN_EPS);
    float4 gv = ((const float4*)g)[tid];
    float4 bv = ((const float4*)bb)[tid];
    float4 ov;
    ov.x = (x[0] - mu) * inv * gv.x + bv.x;
    ov.y = (x[1] - mu) * inv * gv.y + bv.y;
    ov.z = (x[2] - mu) * inv * gv.z + bv.z;
    ov.w = (x[3] - mu) * inv * gv.w + bv.w;
    ((float4*)(y + (size_t)r * 1024))[tid] = ov;
}

extern "C" void kernel_launch(void* const* d_in, const int* in_sizes, int n_in,
                              void* d_out, int out_size, void* d_ws, size_t ws_size,
                              hipStream_t stream) {
    const float* q    = (const float*)d_in[0];
    const float* k    = (const float*)d_in[1];
    const float* v    = (const float*)d_in[2];
    const int*   mask = (const int*)d_in[3];
    const float* wq_w = (const float*)d_in[4];
    const float* wq_b = (const float*)d_in[5];
    const float* wk_w = (const float*)d_in[6];
    const float* wk_b = (const float*)d_in[7];
    const float* wv_w = (const float*)d_in[8];
    const float* wv_b = (const float*)d_in[9];
    const float* fc_w = (const float*)d_in[10];
    const float* fc_b = (const float*)d_in[11];
    const float* ln_g = (const float*)d_in[12];
    const float* ln_b = (const float*)d_in[13];

    char* ws = (char*)d_ws;
    uint16_t* qb  = (uint16_t*)(ws);                    // 8 MB bf16 q
    uint16_t* kb  = (uint16_t*)(ws + (8u << 20));
    uint16_t* vb  = (uint16_t*)(ws + (16u << 20));
    uint16_t* wqb = (uint16_t*)(ws + (24u << 20));      // 2 MB each
    uint16_t* wkb = (uint16_t*)(ws + (26u << 20));
    uint16_t* wvb = (uint16_t*)(ws + (28u << 20));
    uint16_t* wfb = (uint16_t*)(ws + (30u << 20));
    uint16_t* qhb = (uint16_t*)(ws + (32u << 20));      // [bh][l][64]
    uint16_t* khb = (uint16_t*)(ws + (40u << 20));
    uint16_t* vtb = (uint16_t*)(ws + (48u << 20));      // [bh][d][l]
    uint16_t* ctx = (uint16_t*)(ws + (56u << 20));      // [b*l][1024]
    float*    fco = (float*)(ws + (64u << 20));         // 16 MB fp32

    float* y_out = (float*)d_out;
    float* attn_out = y_out + (size_t)4 * 1024 * 1024;

    cvt_bf16<<<dim3(256, 1, 3), 256, 0, stream>>>(q, k, v, nullptr, qb, kb, vb, nullptr, (4 << 20) / 4);
    cvt_bf16<<<dim3(64, 1, 4), 256, 0, stream>>>(wq_w, wk_w, wv_w, fc_w, wqb, wkb, wvb, wfb, (1 << 20) / 4);

    dim3 gg(8, 32);
    gemm_bt<<<gg, 256, 0, stream>>>(qb, wqb, wq_b, qhb, 1024, 0, 0.125f);
    gemm_bt<<<gg, 256, 0, stream>>>(kb, wkb, wk_b, khb, 1024, 0, 1.0f);
    gemm_bt<<<gg, 256, 0, stream>>>(vb, wvb, wv_b, vtb, 1024, 2, 1.0f);

    attn_fused<<<dim3(64, 64), 512, 0, stream>>>(qhb, khb, vtb, mask, attn_out, ctx);

    gemm_bt<<<gg, 256, 0, stream>>>(ctx, wfb, fc_b, fco, 1024, 3, 1.0f);

    fc_ln<<<4096, 256, 0, stream>>>(fco, q, ln_g, ln_b, y_out);
}